// Round 1
// baseline (226.379 us; speedup 1.0000x reference)
//
#include <hip/hip_runtime.h>
#include <math.h>

#define INV_SQRT2 0.7071067811865476f

// ---------------------------------------------------------------------------
// Pass A: accumulate sum(d) and sum(d^2), d = |pred - target|
// ---------------------------------------------------------------------------
__global__ void __launch_bounds__(256)
pass_sums(const float4* __restrict__ pred4, const float4* __restrict__ targ4,
          int n4, const float* __restrict__ pred_s, const float* __restrict__ targ_s,
          int n, float* __restrict__ ws) {
    float s1 = 0.f, s2 = 0.f;
    int idx = blockIdx.x * blockDim.x + threadIdx.x;
    int stride = gridDim.x * blockDim.x;
    for (int i = idx; i < n4; i += stride) {
        float4 p = pred4[i];
        float4 t = targ4[i];
        float d0 = fabsf(p.x - t.x);
        float d1 = fabsf(p.y - t.y);
        float d2 = fabsf(p.z - t.z);
        float d3 = fabsf(p.w - t.w);
        s1 += (d0 + d1) + (d2 + d3);
        s2 += (d0 * d0 + d1 * d1) + (d2 * d2 + d3 * d3);
    }
    // scalar tail (n not divisible by 4) — shape here is divisible, but be safe
    for (int i = n4 * 4 + idx; i < n; i += stride) {
        float d = fabsf(pred_s[i] - targ_s[i]);
        s1 += d;
        s2 += d * d;
    }
    // wave(64) shuffle reduction
    for (int off = 32; off > 0; off >>= 1) {
        s1 += __shfl_down(s1, off);
        s2 += __shfl_down(s2, off);
    }
    __shared__ float ls1[4], ls2[4];
    int lane = threadIdx.x & 63;
    int wid  = threadIdx.x >> 6;
    if (lane == 0) { ls1[wid] = s1; ls2[wid] = s2; }
    __syncthreads();
    if (threadIdx.x == 0) {
        float a = (ls1[0] + ls1[1]) + (ls1[2] + ls1[3]);
        float b = (ls2[0] + ls2[1]) + (ls2[2] + ls2[3]);
        atomicAdd(&ws[0], a);
        atomicAdd(&ws[1], b);
    }
}

// ---------------------------------------------------------------------------
// Pass B: accumulate sum(erf(d / (var*sqrt(2)))); var derived from ws[0..1]
// ---------------------------------------------------------------------------
__global__ void __launch_bounds__(256)
pass_erf(const float4* __restrict__ pred4, const float4* __restrict__ targ4,
         int n4, const float* __restrict__ pred_s, const float* __restrict__ targ_s,
         int n, float* __restrict__ ws) {
    // every thread derives the scalar var (broadcast loads, L2-cached)
    float sum_d  = ws[0];
    float sum_d2 = ws[1];
    float nf     = (float)n;
    float mean_d = sum_d / nf;
    float var    = (sum_d2 - sum_d * mean_d) / (nf - 1.0f);
    float k      = INV_SQRT2 / var;   // erf argument scale

    float s = 0.f;
    int idx = blockIdx.x * blockDim.x + threadIdx.x;
    int stride = gridDim.x * blockDim.x;
    for (int i = idx; i < n4; i += stride) {
        float4 p = pred4[i];
        float4 t = targ4[i];
        float d0 = fabsf(p.x - t.x);
        float d1 = fabsf(p.y - t.y);
        float d2 = fabsf(p.z - t.z);
        float d3 = fabsf(p.w - t.w);
        s += (erff(d0 * k) + erff(d1 * k)) + (erff(d2 * k) + erff(d3 * k));
    }
    for (int i = n4 * 4 + idx; i < n; i += stride) {
        float d = fabsf(pred_s[i] - targ_s[i]);
        s += erff(d * k);
    }
    for (int off = 32; off > 0; off >>= 1)
        s += __shfl_down(s, off);
    __shared__ float ls[4];
    int lane = threadIdx.x & 63;
    int wid  = threadIdx.x >> 6;
    if (lane == 0) ls[wid] = s;
    __syncthreads();
    if (threadIdx.x == 0) {
        float a = (ls[0] + ls[1]) + (ls[2] + ls[3]);
        atomicAdd(&ws[2], a);
    }
}

// ---------------------------------------------------------------------------
// Finalize: scalar math on the three accumulators
// ---------------------------------------------------------------------------
__global__ void finalize(const float* __restrict__ ws, float* __restrict__ out, int n) {
    float sum_d   = ws[0];
    float sum_d2  = ws[1];
    float sum_erf = ws[2];
    float nf      = (float)n;
    float mean_d  = sum_d / nf;
    float var     = (sum_d2 - sum_d * mean_d) / (nf - 1.0f);
    float p       = 1.0f - sum_erf / nf;          // p_correct
    float gamma   = -logf(p);
    float coef    = expf(gamma * logf(1.0f - p)); // (1-p)^gamma
    out[0] = coef * mean_d + logf(var + 1.0f);    // LOSS_WEIGHT = 1
}

extern "C" void kernel_launch(void* const* d_in, const int* in_sizes, int n_in,
                              void* d_out, int out_size, void* d_ws, size_t ws_size,
                              hipStream_t stream) {
    const float* pred = (const float*)d_in[0];
    const float* targ = (const float*)d_in[1];
    float* out = (float*)d_out;
    float* ws  = (float*)d_ws;
    int n  = in_sizes[0];        // 16777216
    int n4 = n >> 2;

    // ws is re-poisoned to 0xAA before every call — zero the 3 accumulators
    hipMemsetAsync(d_ws, 0, 3 * sizeof(float), stream);

    const int block = 256;
    const int grid  = 2048;      // 8 blocks/CU, grid-stride ~8 float4/thread

    pass_sums<<<grid, block, 0, stream>>>((const float4*)pred, (const float4*)targ,
                                          n4, pred, targ, n, ws);
    pass_erf<<<grid, block, 0, stream>>>((const float4*)pred, (const float4*)targ,
                                         n4, pred, targ, n, ws);
    finalize<<<1, 1, 0, stream>>>(ws, out, n);
}

// Round 2
// 209.147 us; speedup vs baseline: 1.0824x; 1.0824x over previous
//
#include <hip/hip_runtime.h>
#include <math.h>

#define INV_SQRT2 0.7071067811865476f

// ---------------------------------------------------------------------------
// Pass A: accumulate sum(d) and sum(d^2), d = |pred - target|
// 4x unrolled grid-stride: 8 independent 16B loads in flight per thread
// before any consumption -> hides ~900cyc HBM latency.
// ---------------------------------------------------------------------------
__global__ void __launch_bounds__(256)
pass_sums(const float4* __restrict__ pred4, const float4* __restrict__ targ4,
          int n4, float* __restrict__ ws) {
    float s1 = 0.f, s2 = 0.f;
    int stride = gridDim.x * blockDim.x;
    int i = blockIdx.x * blockDim.x + threadIdx.x;

    for (; i + 3 * stride < n4; i += 4 * stride) {
        float4 p0 = pred4[i];
        float4 p1 = pred4[i + stride];
        float4 p2 = pred4[i + 2 * stride];
        float4 p3 = pred4[i + 3 * stride];
        float4 t0 = targ4[i];
        float4 t1 = targ4[i + stride];
        float4 t2 = targ4[i + 2 * stride];
        float4 t3 = targ4[i + 3 * stride];

        float d0 = fabsf(p0.x - t0.x), d1 = fabsf(p0.y - t0.y);
        float d2 = fabsf(p0.z - t0.z), d3 = fabsf(p0.w - t0.w);
        float d4 = fabsf(p1.x - t1.x), d5 = fabsf(p1.y - t1.y);
        float d6 = fabsf(p1.z - t1.z), d7 = fabsf(p1.w - t1.w);
        float d8 = fabsf(p2.x - t2.x), d9 = fabsf(p2.y - t2.y);
        float da = fabsf(p2.z - t2.z), db = fabsf(p2.w - t2.w);
        float dc = fabsf(p3.x - t3.x), dd = fabsf(p3.y - t3.y);
        float de = fabsf(p3.z - t3.z), df = fabsf(p3.w - t3.w);

        s1 += ((d0 + d1) + (d2 + d3)) + ((d4 + d5) + (d6 + d7))
            + ((d8 + d9) + (da + db)) + ((dc + dd) + (de + df));
        s2 += ((d0*d0 + d1*d1) + (d2*d2 + d3*d3)) + ((d4*d4 + d5*d5) + (d6*d6 + d7*d7))
            + ((d8*d8 + d9*d9) + (da*da + db*db)) + ((dc*dc + dd*dd) + (de*de + df*df));
    }
    for (; i < n4; i += stride) {
        float4 p = pred4[i];
        float4 t = targ4[i];
        float d0 = fabsf(p.x - t.x), d1 = fabsf(p.y - t.y);
        float d2 = fabsf(p.z - t.z), d3 = fabsf(p.w - t.w);
        s1 += (d0 + d1) + (d2 + d3);
        s2 += (d0*d0 + d1*d1) + (d2*d2 + d3*d3);
    }

    for (int off = 32; off > 0; off >>= 1) {
        s1 += __shfl_down(s1, off);
        s2 += __shfl_down(s2, off);
    }
    __shared__ float ls1[4], ls2[4];
    int lane = threadIdx.x & 63;
    int wid  = threadIdx.x >> 6;
    if (lane == 0) { ls1[wid] = s1; ls2[wid] = s2; }
    __syncthreads();
    if (threadIdx.x == 0) {
        float a = (ls1[0] + ls1[1]) + (ls1[2] + ls1[3]);
        float b = (ls2[0] + ls2[1]) + (ls2[2] + ls2[3]);
        atomicAdd(&ws[0], a);
        atomicAdd(&ws[1], b);
    }
}

// ---------------------------------------------------------------------------
// Pass B: accumulate sum(erf(d * k)), k = 1/(var*sqrt(2)); same 4x unroll.
// ---------------------------------------------------------------------------
__global__ void __launch_bounds__(256)
pass_erf(const float4* __restrict__ pred4, const float4* __restrict__ targ4,
         int n4, int n, float* __restrict__ ws) {
    float sum_d  = ws[0];
    float sum_d2 = ws[1];
    float nf     = (float)n;
    float mean_d = sum_d / nf;
    float var    = (sum_d2 - sum_d * mean_d) / (nf - 1.0f);
    float k      = INV_SQRT2 / var;

    float s = 0.f;
    int stride = gridDim.x * blockDim.x;
    int i = blockIdx.x * blockDim.x + threadIdx.x;

    for (; i + 3 * stride < n4; i += 4 * stride) {
        float4 p0 = pred4[i];
        float4 p1 = pred4[i + stride];
        float4 p2 = pred4[i + 2 * stride];
        float4 p3 = pred4[i + 3 * stride];
        float4 t0 = targ4[i];
        float4 t1 = targ4[i + stride];
        float4 t2 = targ4[i + 2 * stride];
        float4 t3 = targ4[i + 3 * stride];

        s += (erff(fabsf(p0.x - t0.x) * k) + erff(fabsf(p0.y - t0.y) * k))
           + (erff(fabsf(p0.z - t0.z) * k) + erff(fabsf(p0.w - t0.w) * k))
           + (erff(fabsf(p1.x - t1.x) * k) + erff(fabsf(p1.y - t1.y) * k))
           + (erff(fabsf(p1.z - t1.z) * k) + erff(fabsf(p1.w - t1.w) * k))
           + (erff(fabsf(p2.x - t2.x) * k) + erff(fabsf(p2.y - t2.y) * k))
           + (erff(fabsf(p2.z - t2.z) * k) + erff(fabsf(p2.w - t2.w) * k))
           + (erff(fabsf(p3.x - t3.x) * k) + erff(fabsf(p3.y - t3.y) * k))
           + (erff(fabsf(p3.z - t3.z) * k) + erff(fabsf(p3.w - t3.w) * k));
    }
    for (; i < n4; i += stride) {
        float4 p = pred4[i];
        float4 t = targ4[i];
        s += (erff(fabsf(p.x - t.x) * k) + erff(fabsf(p.y - t.y) * k))
           + (erff(fabsf(p.z - t.z) * k) + erff(fabsf(p.w - t.w) * k));
    }

    for (int off = 32; off > 0; off >>= 1)
        s += __shfl_down(s, off);
    __shared__ float ls[4];
    int lane = threadIdx.x & 63;
    int wid  = threadIdx.x >> 6;
    if (lane == 0) ls[wid] = s;
    __syncthreads();
    if (threadIdx.x == 0) {
        float a = (ls[0] + ls[1]) + (ls[2] + ls[3]);
        atomicAdd(&ws[2], a);
    }
}

// ---------------------------------------------------------------------------
// Finalize: scalar math on the three accumulators
// ---------------------------------------------------------------------------
__global__ void finalize(const float* __restrict__ ws, float* __restrict__ out, int n) {
    float sum_d   = ws[0];
    float sum_d2  = ws[1];
    float sum_erf = ws[2];
    float nf      = (float)n;
    float mean_d  = sum_d / nf;
    float var     = (sum_d2 - sum_d * mean_d) / (nf - 1.0f);
    float p       = 1.0f - sum_erf / nf;          // p_correct
    float gamma   = -logf(p);
    float coef    = expf(gamma * logf(1.0f - p)); // (1-p)^gamma
    out[0] = coef * mean_d + logf(var + 1.0f);    // LOSS_WEIGHT = 1
}

extern "C" void kernel_launch(void* const* d_in, const int* in_sizes, int n_in,
                              void* d_out, int out_size, void* d_ws, size_t ws_size,
                              hipStream_t stream) {
    const float* pred = (const float*)d_in[0];
    const float* targ = (const float*)d_in[1];
    float* out = (float*)d_out;
    float* ws  = (float*)d_ws;
    int n  = in_sizes[0];        // 16777216
    int n4 = n >> 2;

    // ws is re-poisoned to 0xAA before every call — zero the 3 accumulators
    hipMemsetAsync(d_ws, 0, 3 * sizeof(float), stream);

    const int block = 256;
    const int grid  = 2048;      // 8 blocks/CU (exactly fills 32 waves/CU)

    pass_sums<<<grid, block, 0, stream>>>((const float4*)pred, (const float4*)targ,
                                          n4, ws);
    pass_erf<<<grid, block, 0, stream>>>((const float4*)pred, (const float4*)targ,
                                         n4, n, ws);
    finalize<<<1, 1, 0, stream>>>(ws, out, n);
}